// Round 5
// baseline (11637.046 us; speedup 1.0000x reference)
//
#include <hip/hip_runtime.h>

// BasicLSTM on MI355X (gfx950) — single mega-kernel, hybrid-coherence h
// exchange: ATOMIC (MALL-direct, sc0/sc1) ring writes + CACHED ring reads
// with one acquire-fence (buffer_inv) per wave per barrier-step.
//
// Consumers (128 blocks): barrier-step s computes layer0 t=s and layer1
// t=s-1. h writes are packed u32 relaxed agent atomics (visible at MALL
// once vmcnt-drained -> no release fence / wbL2 anywhere). h reads are
// plain cached loads; the grid barrier ends with fence(acquire, agent)
// in every wave, so stale L1/L2 lines are invalidated before any h read;
// 16 blocks/XCD then share one MALL refill via L2 (32 MB -> ~2 MB per
// step of MALL traffic). Steady-state steps run a fused passAB
// (8 loads + 24 MFMA per k-iter) for better latency hiding.
// Producers (64 blocks): input GEMM X@Wx0+b0 per chunk into a 2-slot Gc
// ring, 2 chunks ahead, release-fence (wbL2) once per chunk.
//
// Weights: Wh0/Wx1 B-frags in 128 VGPR/wave; Wh1 in 64 KiB LDS; Wx0
// std-pack read by producers. Cell state in registers for the sequence.
//
// Workspace (bytes):
//   WpX  @ 0        : Wx0 std pack                8,388,608
//   WhR0 @ 8388608  : Wh0 per-block frag pack     8,388,608
//   WxR1 @ 16777216 : Wx1 per-block frag pack     8,388,608
//   WhR1 @ 25165824 : Wh1 per-block frag pack     8,388,608
//   ring @ 33554432 : 2 layers x 2 slots x 64x1024 fp16   524,288
//   (pad)@ 34078720 : 524,288 (unused)
//   Gc   @ 34603008 : 2 slots x CH x 64x4096 fp16   2*CH*524,288

typedef _Float16 half8 __attribute__((ext_vector_type(8)));
typedef float    f32x4 __attribute__((ext_vector_type(4)));
typedef unsigned long long u64;
typedef unsigned int u32;

#define SEQ 512
#define BATCH 64
#define HID 1024
#define NCONS 128
#define NPROD 64
#define SLSZ 65536  // BATCH*HID

// sync state (ints): [grp*64] arrive ctr (grp<8); [512] global ctr;
// [576+grp*64] release flags; [1088+c*16] ready ctr; [3136+c*16] done ctr.
__device__ int g_sync[8192];

__global__ void init_bar_k() {
    for (int i = threadIdx.x; i < 8192; i += 256) g_sync[i] = 0;
}

// ---- fallback: write zeros over all of d_out (guarantees >=1 launch) -------
__global__ void zero_out(float* __restrict__ out) {
    size_t i = (size_t)blockIdx.x * blockDim.x + threadIdx.x;
    ((f32x4*)out)[i] = f32x4{0.f, 0.f, 0.f, 0.f};
}

// ---- standard pack: 1024x4096 fp32 -> fp16 B-frags (for producer GEMM) -----
__global__ void pack1(const float* __restrict__ src, _Float16* __restrict__ dst) {
    int nt   = blockIdx.x;        // 0..255
    int ktg  = blockIdx.y;        // 0..7
    int lane = threadIdx.x & 63;
    int wave = threadIdx.x >> 6;
    int kt   = ktg * 4 + wave;    // 0..31
    int k0 = kt * 32 + (lane >> 4) * 8;
    int n  = nt * 16 + (lane & 15);
    half8 v;
#pragma unroll
    for (int j = 0; j < 8; ++j)
        v[j] = (_Float16)src[(size_t)(k0 + j) * 4096 + n];
    *(half8*)(dst + ((size_t)(nt * 32 + kt) * 64 + lane) * 8) = v;
}

// ---- per-block frag pack (consumer weights) --------------------------------
// Block g owns hid cols g*8..g*8+7; tau=0 covers gates {i,j}, tau=1 {f,o}.
__global__ void pack_wh(const float* __restrict__ src, _Float16* __restrict__ dst) {
    int g    = blockIdx.x;        // 0..127
    int ktg  = blockIdx.y;        // 0..7
    int lane = threadIdx.x & 63;
    int wave = threadIdx.x >> 6;
    int kt   = ktg * 4 + wave;    // 0..31
    int c16  = lane & 15;
    int k0   = kt * 32 + (lane >> 4) * 8;
#pragma unroll
    for (int tau = 0; tau < 2; ++tau) {
        int col = (tau * 2 + (c16 >> 3)) * 1024 + g * 8 + (c16 & 7);
        half8 v;
#pragma unroll
        for (int j = 0; j < 8; ++j)
            v[j] = (_Float16)src[(size_t)(k0 + j) * 4096 + col];
        *(half8*)(dst + ((size_t)((g * 2 + tau) * 32 + kt) * 64 + lane) * 8) = v;
    }
}

// ---- producer GEMM tile: 128x128 of G = A(fp32) @ WpX + bias -> fp16 -------
__device__ __forceinline__ void gemm_tile(
    const float* __restrict__ A, const _Float16* __restrict__ Bp,
    const float* __restrict__ bias, _Float16* __restrict__ Gout,
    int mi, int ni)
{
    int lane = threadIdx.x & 63;
    int wave = threadIdx.x >> 6;
    int wm = wave & 1, wn = wave >> 1;
    int m0 = mi * 128 + wm * 64;
    int n0 = ni * 128 + wn * 64;
    int col = lane & 15, quad = lane >> 4;
    f32x4 acc[4][4] = {};
    const float*    Arow  = A + (size_t)(m0 + col) * 1024 + quad * 8;
    const _Float16* Bbase = Bp + (size_t)(n0 >> 4) * 16384 + (size_t)lane * 8;
    for (int kt = 0; kt < 32; ++kt) {
        half8 a[4], b[4];
#pragma unroll
        for (int i = 0; i < 4; ++i) {
            const float* p = Arow + (size_t)i * 16 * 1024 + kt * 32;
            f32x4 v0 = *(const f32x4*)(p);
            f32x4 v1 = *(const f32x4*)(p + 4);
            a[i][0] = (_Float16)v0[0]; a[i][1] = (_Float16)v0[1];
            a[i][2] = (_Float16)v0[2]; a[i][3] = (_Float16)v0[3];
            a[i][4] = (_Float16)v1[0]; a[i][5] = (_Float16)v1[1];
            a[i][6] = (_Float16)v1[2]; a[i][7] = (_Float16)v1[3];
        }
#pragma unroll
        for (int j = 0; j < 4; ++j)
            b[j] = *(const half8*)(Bbase + (size_t)j * 16384 + kt * 512);
#pragma unroll
        for (int i = 0; i < 4; ++i)
#pragma unroll
            for (int j = 0; j < 4; ++j)
                acc[i][j] = __builtin_amdgcn_mfma_f32_16x16x32_f16(a[i], b[j], acc[i][j], 0, 0, 0);
    }
#pragma unroll
    for (int j = 0; j < 4; ++j) {
        int n = n0 + j * 16 + col;
        float bv = bias[n];
#pragma unroll
        for (int i = 0; i < 4; ++i)
#pragma unroll
            for (int r = 0; r < 4; ++r) {
                int m = m0 + i * 16 + quad * 4 + r;
                Gout[(size_t)m * 4096 + n] = (_Float16)(acc[i][j][r] + bv);
            }
    }
}

// ---- hierarchical grid barrier among NCONS consumer blocks -----------------
// Ends with an acquire fence (buffer_inv) in EVERY wave: subsequent plain
// loads of ring h observe the atomic (MALL-direct) stores from other XCDs.
__device__ __forceinline__ void grid_barrier(int n, int grp) {
    asm volatile("s_waitcnt vmcnt(0)" ::: "memory");  // ring/out stores visible
    __syncthreads();
    if (threadIdx.x == 0) {
        int v = __hip_atomic_fetch_add(&g_sync[grp * 64], 1,
                                       __ATOMIC_RELAXED, __HIP_MEMORY_SCOPE_AGENT);
        if (v == n * (NCONS / 8) - 1) {   // last of my 16-block group
            int gv = __hip_atomic_fetch_add(&g_sync[512], 1,
                                            __ATOMIC_RELAXED, __HIP_MEMORY_SCOPE_AGENT);
            if (gv == n * 8 - 1) {        // last group: publish to all 8 flag lines
#pragma unroll
                for (int i = 0; i < 8; ++i)
                    __hip_atomic_store(&g_sync[576 + i * 64], n,
                                       __ATOMIC_RELAXED, __HIP_MEMORY_SCOPE_AGENT);
            }
        }
        while (__hip_atomic_load(&g_sync[576 + grp * 64],
                                 __ATOMIC_RELAXED, __HIP_MEMORY_SCOPE_AGENT) < n)
            __builtin_amdgcn_s_sleep(1);
    }
    __syncthreads();
    __builtin_amdgcn_fence(__ATOMIC_ACQUIRE, "agent");  // inv L1+L2 (per wave)
}

// ---- cached h load (fresh after the per-step acquire fence) ----------------
__device__ __forceinline__ half8 load8(const _Float16* p) {
    return *(const half8*)p;
}

__device__ __forceinline__ half8 cvt_row(const float* p) {
    f32x4 v0 = *(const f32x4*)p, v1 = *(const f32x4*)(p + 4);
    half8 a;
    a[0] = (_Float16)v0[0]; a[1] = (_Float16)v0[1];
    a[2] = (_Float16)v0[2]; a[3] = (_Float16)v0[3];
    a[4] = (_Float16)v1[0]; a[5] = (_Float16)v1[1];
    a[6] = (_Float16)v1[2]; a[7] = (_Float16)v1[3];
    return a;
}

// ---- fused steady-state pass: both h sources, all three weight matrices ----
__device__ __forceinline__ void passAB(
    f32x4 (&acc0)[4][2], f32x4 (&acc1)[4][2],
    const _Float16* __restrict__ h0src, const _Float16* __restrict__ h1src,
    const half8 (&b0)[2][8], const half8 (&b1)[2][8], const half8* smw,
    int wave, int c16, int quad, int lane)
{
#pragma unroll
    for (int i = 0; i < 8; ++i) {
        const int k0 = (wave * 8 + i) * 32 + quad * 8;
        half8 a0[4], a1[4];
#pragma unroll
        for (int m = 0; m < 4; ++m) {
            a0[m] = load8(h0src + (size_t)(m * 16 + c16) * HID + k0);
            a1[m] = load8(h1src + (size_t)(m * 16 + c16) * HID + k0);
        }
        half8 bw0 = smw[(size_t)((0 * 32 + wave * 8 + i) * 64 + lane)];
        half8 bw1 = smw[(size_t)((1 * 32 + wave * 8 + i) * 64 + lane)];
#pragma unroll
        for (int m = 0; m < 4; ++m) {
            acc0[m][0] = __builtin_amdgcn_mfma_f32_16x16x32_f16(a0[m], b0[0][i], acc0[m][0], 0, 0, 0);
            acc0[m][1] = __builtin_amdgcn_mfma_f32_16x16x32_f16(a0[m], b0[1][i], acc0[m][1], 0, 0, 0);
            acc1[m][0] = __builtin_amdgcn_mfma_f32_16x16x32_f16(a0[m], b1[0][i], acc1[m][0], 0, 0, 0);
            acc1[m][1] = __builtin_amdgcn_mfma_f32_16x16x32_f16(a0[m], b1[1][i], acc1[m][1], 0, 0, 0);
            acc1[m][0] = __builtin_amdgcn_mfma_f32_16x16x32_f16(a1[m], bw0, acc1[m][0], 0, 0, 0);
            acc1[m][1] = __builtin_amdgcn_mfma_f32_16x16x32_f16(a1[m], bw1, acc1[m][1], 0, 0, 0);
        }
    }
}

// ---- edge pass A: A = h0-source, feeds acc0 (bh0) and/or acc1 (bx1) --------
template <bool F32, bool DO0, bool DO1>
__device__ __forceinline__ void passA(
    f32x4 (&acc0)[4][2], f32x4 (&acc1)[4][2], const void* src,
    const half8 (&b0)[2][8], const half8 (&b1)[2][8],
    int wave, int c16, int quad)
{
#pragma unroll
    for (int i = 0; i < 8; ++i) {
        const int k0 = (wave * 8 + i) * 32 + quad * 8;
        half8 a[4];
#pragma unroll
        for (int m = 0; m < 4; ++m) {
            if constexpr (F32)
                a[m] = cvt_row((const float*)src + (size_t)(m * 16 + c16) * HID + k0);
            else
                a[m] = load8((const _Float16*)src + (size_t)(m * 16 + c16) * HID + k0);
        }
#pragma unroll
        for (int m = 0; m < 4; ++m) {
            if constexpr (DO0) {
                acc0[m][0] = __builtin_amdgcn_mfma_f32_16x16x32_f16(a[m], b0[0][i], acc0[m][0], 0, 0, 0);
                acc0[m][1] = __builtin_amdgcn_mfma_f32_16x16x32_f16(a[m], b0[1][i], acc0[m][1], 0, 0, 0);
            }
            if constexpr (DO1) {
                acc1[m][0] = __builtin_amdgcn_mfma_f32_16x16x32_f16(a[m], b1[0][i], acc1[m][0], 0, 0, 0);
                acc1[m][1] = __builtin_amdgcn_mfma_f32_16x16x32_f16(a[m], b1[1][i], acc1[m][1], 0, 0, 0);
            }
        }
    }
}

// ---- edge pass B: A = h1-source, B = Wh1 from LDS, feeds acc1 --------------
template <bool F32>
__device__ __forceinline__ void passB(
    f32x4 (&acc1)[4][2], const void* src, const half8* smw,
    int wave, int c16, int quad, int lane)
{
#pragma unroll
    for (int i = 0; i < 8; ++i) {
        const int k0 = (wave * 8 + i) * 32 + quad * 8;
        half8 a[4];
#pragma unroll
        for (int m = 0; m < 4; ++m) {
            if constexpr (F32)
                a[m] = cvt_row((const float*)src + (size_t)(m * 16 + c16) * HID + k0);
            else
                a[m] = load8((const _Float16*)src + (size_t)(m * 16 + c16) * HID + k0);
        }
        half8 bw0 = smw[(size_t)((0 * 32 + wave * 8 + i) * 64 + lane)];
        half8 bw1 = smw[(size_t)((1 * 32 + wave * 8 + i) * 64 + lane)];
#pragma unroll
        for (int m = 0; m < 4; ++m) {
            acc1[m][0] = __builtin_amdgcn_mfma_f32_16x16x32_f16(a[m], bw0, acc1[m][0], 0, 0, 0);
            acc1[m][1] = __builtin_amdgcn_mfma_f32_16x16x32_f16(a[m], bw1, acc1[m][1], 0, 0, 0);
        }
    }
}

// ---- LSTM cell epilogue: gates -> (c,h), MALL-direct packed ring store -----
__device__ __forceinline__ void cell_epilogue(
    const f32x4 (&fin)[2], float (&creg)[4], _Float16* rw, float* outp,
    float* lh, float* lc, int rbase, int hcol, int c16, bool owner)
{
#pragma unroll
    for (int r = 0; r < 4; ++r) {
        float v0 = fin[0][r], v1 = fin[1][r];
        float x0 = __shfl_xor(v0, 8), x1 = __shfl_xor(v1, 8);
        float gi = owner ? v0 : x0, gj = owner ? x0 : v0;
        float gf = owner ? v1 : x1, go = owner ? x1 : v1;
        float iv = 1.f / (1.f + __expf(-gi));
        float jv = tanhf(gj);
        float fv = 1.f / (1.f + __expf(-gf));
        float ov = 1.f / (1.f + __expf(-go));
        float cn = creg[r] * fv + iv * jv;
        float hn = tanhf(cn) * ov;
        creg[r] = cn;
        union { _Float16 f; unsigned short s; } cv; cv.f = (_Float16)hn;
        u32 other = (u32)(unsigned short)__shfl_xor((int)cv.s, 1);
        size_t idx = (size_t)(rbase + r) * HID + hcol;
        if (owner) {
            if (outp) outp[idx] = hn;
            if (lh) { lh[idx] = hn; lc[idx] = cn; }
            if (!(c16 & 1)) {
                u32 pk = (u32)cv.s | (other << 16);
                __hip_atomic_store((u32*)(rw + idx), pk,
                                   __ATOMIC_RELAXED, __HIP_MEMORY_SCOPE_AGENT);
            }
        }
    }
}

// ---- producer path: input GEMM chunks, 2 ahead of consumers ----------------
__device__ __forceinline__ void producer_path(
    const _Float16* __restrict__ WpX, const float* __restrict__ X,
    const float* __restrict__ bias0, _Float16* __restrict__ Gc,
    int nchunk, int ch)
{
    const int p = blockIdx.x;                    // 0..63
    const int rows = ch * 64;
    const int tpp = (rows / 128) * 32 / NPROD;   // 2 (ch=8) or 1 (ch=4)
    const size_t slotsz = (size_t)ch * 4 * SLSZ; // halfs
    for (int c = 0; c < nchunk; ++c) {
        if (c >= 2) {    // WAR: slot (c&1) free once consumers finished c-2
            if (threadIdx.x == 0)
                while (__hip_atomic_load(&g_sync[3136 + (c - 2) * 16],
                                         __ATOMIC_RELAXED, __HIP_MEMORY_SCOPE_AGENT) < NCONS)
                    __builtin_amdgcn_s_sleep(4);
            __syncthreads();
        }
        const float* A = X + (size_t)c * rows * 1024;
        _Float16* Gout = Gc + (size_t)(c & 1) * slotsz;
        for (int tt = 0; tt < tpp; ++tt) {
            int T = p * tpp + tt;
            gemm_tile(A, WpX, bias0, Gout, T >> 5, T & 31);
        }
        asm volatile("s_waitcnt vmcnt(0)" ::: "memory");  // all waves' stores in L2
        __syncthreads();
        if (threadIdx.x == 0) {
            __builtin_amdgcn_fence(__ATOMIC_RELEASE, "agent");  // wbL2 -> MALL
            __hip_atomic_fetch_add(&g_sync[1088 + c * 16], 1,
                                   __ATOMIC_RELAXED, __HIP_MEMORY_SCOPE_AGENT);
        }
        __syncthreads();
    }
}

// ---- consumer path: the two-layer pipelined recurrence ---------------------
__device__ __forceinline__ void consumer_path(
    int g, const _Float16* __restrict__ WhR0, const _Float16* __restrict__ WxR1,
    const _Float16* __restrict__ WhR1, const _Float16* __restrict__ Gc,
    const float* __restrict__ hinit, const float* __restrict__ cinit,
    _Float16* __restrict__ ring, float* __restrict__ out,
    const float* __restrict__ bias1, int ch)
{
    const int lane = threadIdx.x & 63;
    const int wave = threadIdx.x >> 6;
    const int c16 = lane & 15, quad = lane >> 4;
    const int hcol = g * 8 + (c16 & 7);
    const bool owner = (c16 < 8);
    const int rbase = wave * 16 + quad * 4;
    const int grp = g & 7;
    const size_t slotsz = (size_t)ch * 4 * SLSZ;

    __shared__ half8 smw[4096];           // Wh1 block slice, 64 KiB
    __shared__ f32x4 red0[3][4][2][64];   // 24 KiB
    __shared__ f32x4 red1[3][4][2][64];   // 24 KiB

    _Float16* ring0 = ring;
    _Float16* ring1 = ring + 2 * SLSZ;
    const size_t FO = (size_t)SEQ * SLSZ;

    // Wh1 -> LDS
    {
        const _Float16* wsrc = WhR1 + (size_t)g * 32768;
        for (int i = threadIdx.x; i < 4096; i += 256)
            smw[i] = *(const half8*)(wsrc + (size_t)i * 8);
    }
    // bh0, bx1 register-resident
    half8 bh0[2][8], bx1[2][8];
#pragma unroll
    for (int tau = 0; tau < 2; ++tau)
#pragma unroll
        for (int i = 0; i < 8; ++i) {
            size_t off = ((size_t)((g * 2 + tau) * 32 + wave * 8 + i) * 64 + lane) * 8;
            bh0[tau][i] = *(const half8*)(WhR0 + off);
            bx1[tau][i] = *(const half8*)(WxR1 + off);
        }
    float bv1[2];
#pragma unroll
    for (int tau = 0; tau < 2; ++tau)
        bv1[tau] = bias1[(tau * 2 + (c16 >> 3)) * 1024 + hcol];

    float creg0[4], creg1[4];
#pragma unroll
    for (int r = 0; r < 4; ++r) {
        creg0[r] = cinit[(size_t)(rbase + r) * HID + hcol];
        creg1[r] = cinit[SLSZ + (size_t)(rbase + r) * HID + hcol];
    }

    const int colG0 = (c16 >> 3) * 1024 + hcol;
    __syncthreads();  // smw ready

    for (int sidx = 0; sidx <= SEQ; ++sidx) {
        const int s = sidx, t1 = s - 1;
        const bool do0 = (s < SEQ), do1 = (t1 >= 0);
        int cchunk = 0, tl = 0;
        if (do0) { cchunk = s / ch; tl = s - cchunk * ch; }

        // chunk gate: wait for producers, then one acquire-inv for the chunk
        if (do0 && tl == 0) {
            if (threadIdx.x == 0) {
                while (__hip_atomic_load(&g_sync[1088 + cchunk * 16],
                                         __ATOMIC_RELAXED, __HIP_MEMORY_SCOPE_AGENT) < NPROD)
                    __builtin_amdgcn_s_sleep(1);
                __builtin_amdgcn_fence(__ATOMIC_ACQUIRE, "agent");  // inv
            }
            __syncthreads();
        }

        // acc inits + G prefetch (plain cached loads, slot stable this chunk)
        f32x4 acc0[4][2], acc1[4][2];
#pragma unroll
        for (int m = 0; m < 4; ++m)
#pragma unroll
            for (int tau = 0; tau < 2; ++tau) {
                acc0[m][tau] = f32x4{0.f, 0.f, 0.f, 0.f};
                acc1[m][tau] = f32x4{0.f, 0.f, 0.f, 0.f};
            }
#pragma unroll
        for (int m = 0; m < 4; ++m)
            if (m == wave) {
                acc1[m][0] = f32x4{bv1[0], bv1[0], bv1[0], bv1[0]};
                acc1[m][1] = f32x4{bv1[1], bv1[1], bv1[1], bv1[1]};
            }
        if (do0) {
            const _Float16* Gt = Gc + (size_t)(cchunk & 1) * slotsz + (size_t)tl * 4 * SLSZ;
#pragma unroll
            for (int tau = 0; tau < 2; ++tau) {
                f32x4 v;
#pragma unroll
                for (int r = 0; r < 4; ++r)
                    v[r] = (float)Gt[(size_t)(rbase + r) * 4096 + tau * 2048 + colG0];
#pragma unroll
                for (int m = 0; m < 4; ++m)
                    if (m == wave) acc0[m][tau] = v;
            }
        }

        if (sidx > 0) grid_barrier(sidx, grp);
        // after barrier: all consumers' G loads for the chunk's last step done
        if (do0 && tl == ch - 1 && threadIdx.x == 0)
            __hip_atomic_fetch_add(&g_sync[3136 + cchunk * 16], 1,
                                   __ATOMIC_RELAXED, __HIP_MEMORY_SCOPE_AGENT);

        const _Float16* h0prev = ring0 + (size_t)((s - 1) & 1) * SLSZ;
        if (do0 && do1 && t1 > 0) {
            // steady state: fused pass over both h sources
            passAB(acc0, acc1, h0prev,
                   ring1 + (size_t)((t1 - 1) & 1) * SLSZ,
                   bh0, bx1, smw, wave, c16, quad, lane);
        } else {
            if (do0 && do1)        // s == 1 (t1 == 0)
                passA<false, true, true>(acc0, acc1, h0prev, bh0, bx1, wave, c16, quad);
            else if (do0)          // s == 0
                passA<true, true, false>(acc0, acc1, hinit, bh0, bx1, wave, c16, quad);
            else                   // s == SEQ (drain)
                passA<false, false, true>(acc0, acc1, h0prev, bh0, bx1, wave, c16, quad);
            if (do1) {
                if (t1 == 0)
                    passB<true>(acc1, hinit + SLSZ, smw, wave, c16, quad, lane);
                else
                    passB<false>(acc1, ring1 + (size_t)((t1 - 1) & 1) * SLSZ, smw,
                                 wave, c16, quad, lane);
            }
        }

        // cross-wave K reduction (wave w finalizes m-tile w)
        if (do0) {
#pragma unroll
            for (int m = 0; m < 4; ++m)
                if (m != wave) {
                    int slot = wave - (wave > m ? 1 : 0);
#pragma unroll
                    for (int tau = 0; tau < 2; ++tau)
                        red0[slot][m][tau][lane] = acc0[m][tau];
                }
        }
        if (do1) {
#pragma unroll
            for (int m = 0; m < 4; ++m)
                if (m != wave) {
                    int slot = wave - (wave > m ? 1 : 0);
#pragma unroll
                    for (int tau = 0; tau < 2; ++tau)
                        red1[slot][m][tau][lane] = acc1[m][tau];
                }
        }
        f32x4 own0[2], own1[2];
        own0[0] = acc0[0][0]; own0[1] = acc0[0][1];
        own1[0] = acc1[0][0]; own1[1] = acc1[0][1];
#pragma unroll
        for (int m = 1; m < 4; ++m)
            if (wave == m) {
                own0[0] = acc0[m][0]; own0[1] = acc0[m][1];
                own1[0] = acc1[m][0]; own1[1] = acc1[m][1];
            }
        __syncthreads();

        // epilogues
        if (do0) {
            f32x4 fin[2];
#pragma unroll
            for (int tau = 0; tau < 2; ++tau) {
                f32x4 ssum = own0[tau];
#pragma unroll
                for (int v = 0; v < 3; ++v) ssum += red0[v][wave][tau][lane];
                fin[tau] = ssum;
            }
            float* lh = (s == SEQ - 1) ? out + FO : nullptr;
            float* lc = (s == SEQ - 1) ? out + FO + 2 * SLSZ : nullptr;
            cell_epilogue(fin, creg0, ring0 + (size_t)(s & 1) * SLSZ,
                          nullptr, lh, lc, rbase, hcol, c16, owner);
        }
        if (do1) {
            f32x4 fin[2];
#pragma unroll
            for (int tau = 0; tau < 2; ++tau) {
                f32x4 ssum = own1[tau];
#pragma unroll
                for (int v = 0; v < 3; ++v) ssum += red1[v][wave][tau][lane];
                fin[tau] = ssum;
            }
            float* lh = (t1 == SEQ - 1) ? out + FO + SLSZ : nullptr;
            float* lc = (t1 == SEQ - 1) ? out + FO + 3 * SLSZ : nullptr;
            cell_epilogue(fin, creg1, ring1 + (size_t)(t1 & 1) * SLSZ,
                          out + (size_t)t1 * SLSZ, lh, lc, rbase, hcol, c16, owner);
        }
    }
}

// ---- mega kernel: 64 producers + 128 consumers, one launch -----------------
__global__ __launch_bounds__(256, 1) void lstm_mega(
    const _Float16* __restrict__ WpX, const _Float16* __restrict__ WhR0,
    const _Float16* __restrict__ WxR1, const _Float16* __restrict__ WhR1,
    _Float16* __restrict__ Gc, const float* __restrict__ X,
    const float* __restrict__ hinit, const float* __restrict__ cinit,
    _Float16* __restrict__ ring, float* __restrict__ out,
    const float* __restrict__ bias0, const float* __restrict__ bias1,
    int nchunk, int ch)
{
    if (blockIdx.x < NPROD) {
        producer_path(WpX, X, bias0, Gc, nchunk, ch);
        return;
    }
    consumer_path((int)blockIdx.x - NPROD, WhR0, WxR1, WhR1, Gc,
                  hinit, cinit, ring, out, bias1, ch);
}

extern "C" void kernel_launch(void* const* d_in, const int* in_sizes, int n_in,
                              void* d_out, int out_size, void* d_ws, size_t ws_size,
                              hipStream_t stream) {
    const float* X  = (const float*)d_in[0];
    const float* h0 = (const float*)d_in[1];
    const float* c0 = (const float*)d_in[2];
    const float* W  = (const float*)d_in[3];
    const float* bb = (const float*)d_in[4];
    float* out = (float*)d_out;
    char* ws = (char*)d_ws;

    const size_t FIXED = 34603008ULL;
    int CH = 0;
    if (ws_size >= FIXED + 2ULL * 8 * 524288ULL)      CH = 8;   // 2 slots x 4 MB
    else if (ws_size >= FIXED + 2ULL * 4 * 524288ULL) CH = 4;   // 2 slots x 2 MB
    if (CH == 0) {
        zero_out<<<dim3(33024), 256, 0, stream>>>(out);
        return;
    }

    _Float16* WpX  = (_Float16*)(ws + 0);
    _Float16* WhR0 = (_Float16*)(ws + 8388608);
    _Float16* WxR1 = (_Float16*)(ws + 16777216);
    _Float16* WhR1 = (_Float16*)(ws + 25165824);
    _Float16* ring = (_Float16*)(ws + 33554432);
    _Float16* Gc   = (_Float16*)(ws + 34603008);

    const size_t MSTRIDE = 2048ULL * 4096ULL;   // per-layer W block (floats)

    pack1<<<dim3(256, 8), 256, 0, stream>>>(W, WpX);                             // Wx0
    pack_wh<<<dim3(NCONS, 8), 256, 0, stream>>>(W + 1024 * 4096, WhR0);          // Wh0
    pack_wh<<<dim3(NCONS, 8), 256, 0, stream>>>(W + MSTRIDE, WxR1);              // Wx1
    pack_wh<<<dim3(NCONS, 8), 256, 0, stream>>>(W + MSTRIDE + 1024 * 4096, WhR1);// Wh1
    init_bar_k<<<dim3(1), 256, 0, stream>>>();

    lstm_mega<<<dim3(NPROD + NCONS), 256, 0, stream>>>(
        WpX, WhR0, WxR1, WhR1, Gc, X, h0, c0, ring, out,
        bb, bb + 4096, SEQ / CH, CH);
}

// Round 6
// 10887.891 us; speedup vs baseline: 1.0688x; 1.0688x over previous
//
#include <hip/hip_runtime.h>

// BasicLSTM on MI355X (gfx950) — single mega-kernel, 8-wave consumers
// (K-split 8, 2 waves/SIMD), all weights register-resident per K-slice.
//
// Consumers (128 blocks x 512 thr): barrier-step s computes layer0 t=s and
// layer1 t=s-1. Each wave owns K-slice [wave*128, wave*128+128) and holds
// its slice of Wh0/Wx1/Wh1 B-frags in 96 VGPRs. Partials for all
// (layer, m-tile, tau) go to 128 KiB LDS; one __syncthreads; wave w
// finalizes (layer=w&1, m=w>>1): sums 8 partials, adds G/bias, runs the
// LSTM cell, stores h via MALL-direct packed u32 agent atomics.
// h reads are relaxed agent atomic u64 pairs (no fences needed).
// Hierarchical grid barrier (8 groups -> global -> replicated flags).
// Producers (32 blocks x 512 thr = 64 tile engines): X@Wx0+b0 per chunk
// into a 2-slot Gc ring, 2 chunks ahead; one wbL2 release per chunk;
// consumers one inv acquire per chunk.
//
// Workspace (bytes):
//   WpX  @ 0        : Wx0 std pack                8,388,608
//   WhR0 @ 8388608  : Wh0 per-block frag pack     8,388,608
//   WxR1 @ 16777216 : Wx1 per-block frag pack     8,388,608
//   WhR1 @ 25165824 : Wh1 per-block frag pack     8,388,608
//   ring @ 33554432 : 2 layers x 2 slots x 64x1024 fp16   524,288
//   (pad)@ 34078720 : 524,288 (unused)
//   Gc   @ 34603008 : 2 slots x CH x 64x4096 fp16   2*CH*524,288

typedef _Float16 half8 __attribute__((ext_vector_type(8)));
typedef float    f32x4 __attribute__((ext_vector_type(4)));
typedef unsigned long long u64;
typedef unsigned int u32;

#define SEQ 512
#define BATCH 64
#define HID 1024
#define NCONS 128
#define NPROD 32
#define SLSZ 65536  // BATCH*HID

// sync state (ints): [grp*64] arrive ctr (grp<8); [512] global ctr;
// [576+grp*64] release flags; [1088+c*16] ready ctr; [3136+c*16] done ctr.
__device__ int g_sync[8192];

__global__ void init_bar_k() {
    for (int i = threadIdx.x; i < 8192; i += 256) g_sync[i] = 0;
}

// ---- fallback: write zeros over all of d_out (guarantees >=1 launch) -------
__global__ void zero_out(float* __restrict__ out) {
    size_t i = (size_t)blockIdx.x * blockDim.x + threadIdx.x;
    ((f32x4*)out)[i] = f32x4{0.f, 0.f, 0.f, 0.f};
}

// ---- standard pack: 1024x4096 fp32 -> fp16 B-frags (for producer GEMM) -----
__global__ void pack1(const float* __restrict__ src, _Float16* __restrict__ dst) {
    int nt   = blockIdx.x;        // 0..255
    int ktg  = blockIdx.y;        // 0..7
    int lane = threadIdx.x & 63;
    int wave = threadIdx.x >> 6;
    int kt   = ktg * 4 + wave;    // 0..31
    int k0 = kt * 32 + (lane >> 4) * 8;
    int n  = nt * 16 + (lane & 15);
    half8 v;
#pragma unroll
    for (int j = 0; j < 8; ++j)
        v[j] = (_Float16)src[(size_t)(k0 + j) * 4096 + n];
    *(half8*)(dst + ((size_t)(nt * 32 + kt) * 64 + lane) * 8) = v;
}

// ---- per-block frag pack (consumer weights) --------------------------------
// Block g owns hid cols g*8..g*8+7; tau=0 covers gates {i,j}, tau=1 {f,o}.
__global__ void pack_wh(const float* __restrict__ src, _Float16* __restrict__ dst) {
    int g    = blockIdx.x;        // 0..127
    int ktg  = blockIdx.y;        // 0..7
    int lane = threadIdx.x & 63;
    int wave = threadIdx.x >> 6;
    int kt   = ktg * 4 + wave;    // 0..31
    int c16  = lane & 15;
    int k0   = kt * 32 + (lane >> 4) * 8;
#pragma unroll
    for (int tau = 0; tau < 2; ++tau) {
        int col = (tau * 2 + (c16 >> 3)) * 1024 + g * 8 + (c16 & 7);
        half8 v;
#pragma unroll
        for (int j = 0; j < 8; ++j)
            v[j] = (_Float16)src[(size_t)(k0 + j) * 4096 + col];
        *(half8*)(dst + ((size_t)((g * 2 + tau) * 32 + kt) * 64 + lane) * 8) = v;
    }
}

// ---- producer GEMM tile: 128x128 of G = A(fp32) @ WpX + bias -> fp16 -------
// tid is a 256-thread sub-block index (two engines per 512-thread block).
__device__ __forceinline__ void gemm_tile(
    const float* __restrict__ A, const _Float16* __restrict__ Bp,
    const float* __restrict__ bias, _Float16* __restrict__ Gout,
    int mi, int ni, int tid)
{
    int lane = tid & 63;
    int wave = (tid >> 6) & 3;
    int wm = wave & 1, wn = wave >> 1;
    int m0 = mi * 128 + wm * 64;
    int n0 = ni * 128 + wn * 64;
    int col = lane & 15, quad = lane >> 4;
    f32x4 acc[4][4] = {};
    const float*    Arow  = A + (size_t)(m0 + col) * 1024 + quad * 8;
    const _Float16* Bbase = Bp + (size_t)(n0 >> 4) * 16384 + (size_t)lane * 8;
    for (int kt = 0; kt < 32; ++kt) {
        half8 a[4], b[4];
#pragma unroll
        for (int i = 0; i < 4; ++i) {
            const float* p = Arow + (size_t)i * 16 * 1024 + kt * 32;
            f32x4 v0 = *(const f32x4*)(p);
            f32x4 v1 = *(const f32x4*)(p + 4);
            a[i][0] = (_Float16)v0[0]; a[i][1] = (_Float16)v0[1];
            a[i][2] = (_Float16)v0[2]; a[i][3] = (_Float16)v0[3];
            a[i][4] = (_Float16)v1[0]; a[i][5] = (_Float16)v1[1];
            a[i][6] = (_Float16)v1[2]; a[i][7] = (_Float16)v1[3];
        }
#pragma unroll
        for (int j = 0; j < 4; ++j)
            b[j] = *(const half8*)(Bbase + (size_t)j * 16384 + kt * 512);
#pragma unroll
        for (int i = 0; i < 4; ++i)
#pragma unroll
            for (int j = 0; j < 4; ++j)
                acc[i][j] = __builtin_amdgcn_mfma_f32_16x16x32_f16(a[i], b[j], acc[i][j], 0, 0, 0);
    }
#pragma unroll
    for (int j = 0; j < 4; ++j) {
        int n = n0 + j * 16 + col;
        float bv = bias[n];
#pragma unroll
        for (int i = 0; i < 4; ++i)
#pragma unroll
            for (int r = 0; r < 4; ++r) {
                int m = m0 + i * 16 + quad * 4 + r;
                Gout[(size_t)m * 4096 + n] = (_Float16)(acc[i][j][r] + bv);
            }
    }
}

// ---- hierarchical grid barrier among NCONS consumer blocks -----------------
__device__ __forceinline__ void grid_barrier(int n, int grp) {
    asm volatile("s_waitcnt vmcnt(0)" ::: "memory");  // ring/out stores visible
    __syncthreads();
    if (threadIdx.x == 0) {
        int v = __hip_atomic_fetch_add(&g_sync[grp * 64], 1,
                                       __ATOMIC_RELAXED, __HIP_MEMORY_SCOPE_AGENT);
        if (v == n * (NCONS / 8) - 1) {   // last of my 16-block group
            int gv = __hip_atomic_fetch_add(&g_sync[512], 1,
                                            __ATOMIC_RELAXED, __HIP_MEMORY_SCOPE_AGENT);
            if (gv == n * 8 - 1) {        // last group: publish to all 8 flag lines
#pragma unroll
                for (int i = 0; i < 8; ++i)
                    __hip_atomic_store(&g_sync[576 + i * 64], n,
                                       __ATOMIC_RELAXED, __HIP_MEMORY_SCOPE_AGENT);
            }
        }
        while (__hip_atomic_load(&g_sync[576 + grp * 64],
                                 __ATOMIC_RELAXED, __HIP_MEMORY_SCOPE_AGENT) < n)
            __builtin_amdgcn_s_sleep(1);
    }
    __syncthreads();
}

// ---- coherent (cross-XCD) h load -------------------------------------------
__device__ __forceinline__ half8 cload8(const _Float16* p) {
    union { half8 h; u64 u[2]; } x;
    x.u[0] = __hip_atomic_load((const u64*)p, __ATOMIC_RELAXED, __HIP_MEMORY_SCOPE_AGENT);
    x.u[1] = __hip_atomic_load((const u64*)p + 1, __ATOMIC_RELAXED, __HIP_MEMORY_SCOPE_AGENT);
    return x.h;
}

__device__ __forceinline__ half8 cvt_row(const float* p) {
    f32x4 v0 = *(const f32x4*)p, v1 = *(const f32x4*)(p + 4);
    half8 a;
    a[0] = (_Float16)v0[0]; a[1] = (_Float16)v0[1];
    a[2] = (_Float16)v0[2]; a[3] = (_Float16)v0[3];
    a[4] = (_Float16)v1[0]; a[5] = (_Float16)v1[1];
    a[6] = (_Float16)v1[2]; a[7] = (_Float16)v1[3];
    return a;
}

// ---- K-slice pass: MODE 0 steady, 1 s==0, 2 s==1 (h1 from init), 3 s==SEQ --
template <int MODE>
__device__ __forceinline__ void kpass(
    f32x4 (&acc0)[4][2], f32x4 (&acc1)[4][2],
    const _Float16* __restrict__ h0f16, const float* __restrict__ h0f32,
    const _Float16* __restrict__ h1f16, const float* __restrict__ h1f32,
    const half8 (&bh0)[2][4], const half8 (&bx1)[2][4], const half8 (&bh1)[2][4],
    int wave, int c16, int quad)
{
#pragma unroll
    for (int i = 0; i < 4; ++i) {
        const int k0 = (wave * 4 + i) * 32 + quad * 8;
        half8 a0[4], a1[4];
#pragma unroll
        for (int m = 0; m < 4; ++m) {
            if constexpr (MODE == 1)
                a0[m] = cvt_row(h0f32 + (size_t)(m * 16 + c16) * HID + k0);
            else
                a0[m] = cload8(h0f16 + (size_t)(m * 16 + c16) * HID + k0);
        }
        if constexpr (MODE == 0 || MODE == 3) {
#pragma unroll
            for (int m = 0; m < 4; ++m)
                a1[m] = cload8(h1f16 + (size_t)(m * 16 + c16) * HID + k0);
        } else if constexpr (MODE == 2) {
#pragma unroll
            for (int m = 0; m < 4; ++m)
                a1[m] = cvt_row(h1f32 + (size_t)(m * 16 + c16) * HID + k0);
        }
#pragma unroll
        for (int m = 0; m < 4; ++m) {
            if constexpr (MODE != 3) {
                acc0[m][0] = __builtin_amdgcn_mfma_f32_16x16x32_f16(a0[m], bh0[0][i], acc0[m][0], 0, 0, 0);
                acc0[m][1] = __builtin_amdgcn_mfma_f32_16x16x32_f16(a0[m], bh0[1][i], acc0[m][1], 0, 0, 0);
            }
            if constexpr (MODE != 1) {
                acc1[m][0] = __builtin_amdgcn_mfma_f32_16x16x32_f16(a0[m], bx1[0][i], acc1[m][0], 0, 0, 0);
                acc1[m][1] = __builtin_amdgcn_mfma_f32_16x16x32_f16(a0[m], bx1[1][i], acc1[m][1], 0, 0, 0);
                acc1[m][0] = __builtin_amdgcn_mfma_f32_16x16x32_f16(a1[m], bh1[0][i], acc1[m][0], 0, 0, 0);
                acc1[m][1] = __builtin_amdgcn_mfma_f32_16x16x32_f16(a1[m], bh1[1][i], acc1[m][1], 0, 0, 0);
            }
        }
    }
}

// ---- LSTM cell epilogue: gates -> (c,h), MALL-direct packed ring store -----
__device__ __forceinline__ void cell_epilogue(
    const f32x4 (&fin)[2], float (&creg)[4], _Float16* rw, float* outp,
    float* lh, float* lc, int rbase, int hcol, int c16, bool owner)
{
#pragma unroll
    for (int r = 0; r < 4; ++r) {
        float v0 = fin[0][r], v1 = fin[1][r];
        float x0 = __shfl_xor(v0, 8), x1 = __shfl_xor(v1, 8);
        float gi = owner ? v0 : x0, gj = owner ? x0 : v0;
        float gf = owner ? v1 : x1, go = owner ? x1 : v1;
        float iv = 1.f / (1.f + __expf(-gi));
        float jv = tanhf(gj);
        float fv = 1.f / (1.f + __expf(-gf));
        float ov = 1.f / (1.f + __expf(-go));
        float cn = creg[r] * fv + iv * jv;
        float hn = tanhf(cn) * ov;
        creg[r] = cn;
        union { _Float16 f; unsigned short s; } cv; cv.f = (_Float16)hn;
        u32 other = (u32)(unsigned short)__shfl_xor((int)cv.s, 1);
        size_t idx = (size_t)(rbase + r) * HID + hcol;
        if (owner) {
            if (outp) outp[idx] = hn;
            if (lh) { lh[idx] = hn; lc[idx] = cn; }
            if (!(c16 & 1)) {
                u32 pk = (u32)cv.s | (other << 16);
                __hip_atomic_store((u32*)(rw + idx), pk,
                                   __ATOMIC_RELAXED, __HIP_MEMORY_SCOPE_AGENT);
            }
        }
    }
}

// ---- producer path: input GEMM chunks, 2 ahead of consumers ----------------
__device__ __forceinline__ void producer_path(
    const _Float16* __restrict__ WpX, const float* __restrict__ X,
    const float* __restrict__ bias0, _Float16* __restrict__ Gc,
    int nchunk, int ch)
{
    const int p = blockIdx.x;                      // 0..31
    const int half = threadIdx.x >> 8;             // two 256-thread engines
    const int tid = threadIdx.x & 255;
    const int rows = ch * 64;
    const int tiles = (rows / 128) * 32;           // 128 (ch=8) / 64 (ch=4)
    const int tpp = tiles / (NPROD * 2);           // 2 / 1
    const size_t slotsz = (size_t)ch * 4 * SLSZ;   // halfs
    for (int c = 0; c < nchunk; ++c) {
        if (c >= 2) {    // WAR: slot (c&1) free once consumers finished c-2
            if (threadIdx.x == 0)
                while (__hip_atomic_load(&g_sync[3136 + (c - 2) * 16],
                                         __ATOMIC_RELAXED, __HIP_MEMORY_SCOPE_AGENT) < NCONS)
                    __builtin_amdgcn_s_sleep(4);
            __syncthreads();
        }
        const float* A = X + (size_t)c * rows * 1024;
        _Float16* Gout = Gc + (size_t)(c & 1) * slotsz;
        for (int tt = 0; tt < tpp; ++tt) {
            int T = (p * 2 + half) * tpp + tt;
            gemm_tile(A, WpX, bias0, Gout, T >> 5, T & 31, tid);
        }
        asm volatile("s_waitcnt vmcnt(0)" ::: "memory");  // all stores in L2
        __syncthreads();
        if (threadIdx.x == 0) {
            __builtin_amdgcn_fence(__ATOMIC_RELEASE, "agent");  // wbL2 -> MALL
            __hip_atomic_fetch_add(&g_sync[1088 + c * 16], 1,
                                   __ATOMIC_RELAXED, __HIP_MEMORY_SCOPE_AGENT);
        }
        __syncthreads();
    }
}

// ---- consumer path: two-layer pipelined recurrence, 8 waves, K-split 8 -----
__device__ __forceinline__ void consumer_path(
    int g, const _Float16* __restrict__ WhR0, const _Float16* __restrict__ WxR1,
    const _Float16* __restrict__ WhR1, const _Float16* __restrict__ Gc,
    const float* __restrict__ hinit, const float* __restrict__ cinit,
    _Float16* __restrict__ ring, float* __restrict__ out,
    const float* __restrict__ bias1, int ch)
{
    const int lane = threadIdx.x & 63;
    const int wave = threadIdx.x >> 6;     // 0..7
    const int c16 = lane & 15, quad = lane >> 4;
    const int hcol = g * 8 + (c16 & 7);
    const bool owner = (c16 < 8);
    const int grp = g & 7;
    const size_t slotsz = (size_t)ch * 4 * SLSZ;

    __shared__ f32x4 redA[8][4][2][64];   // layer0 partials, 64 KiB
    __shared__ f32x4 redB[8][4][2][64];   // layer1 partials, 64 KiB

    _Float16* ring0 = ring;
    _Float16* ring1 = ring + 2 * SLSZ;
    const size_t FO = (size_t)SEQ * SLSZ;

    // per-wave K-slice of all three weight matrices (96 VGPR)
    half8 bh0[2][4], bx1[2][4], bh1[2][4];
#pragma unroll
    for (int tau = 0; tau < 2; ++tau)
#pragma unroll
        for (int i = 0; i < 4; ++i) {
            size_t off = ((size_t)((g * 2 + tau) * 32 + wave * 4 + i) * 64 + lane) * 8;
            bh0[tau][i] = *(const half8*)(WhR0 + off);
            bx1[tau][i] = *(const half8*)(WxR1 + off);
            bh1[tau][i] = *(const half8*)(WhR1 + off);
        }

    // finalizer role: layer l = wave&1, m-tile mi = wave>>1
    const int l = wave & 1, mi = wave >> 1;
    const int rbase = mi * 16 + quad * 4;
    float bv1[2];
#pragma unroll
    for (int tau = 0; tau < 2; ++tau)
        bv1[tau] = bias1[(tau * 2 + (c16 >> 3)) * 1024 + hcol];
    float creg[4];
#pragma unroll
    for (int r = 0; r < 4; ++r)
        creg[r] = cinit[(size_t)l * SLSZ + (size_t)(rbase + r) * HID + hcol];

    const int colG0 = (c16 >> 3) * 1024 + hcol;

    for (int sidx = 0; sidx <= SEQ; ++sidx) {
        const int s = sidx, t1 = s - 1;
        const bool do0 = (s < SEQ), do1 = (t1 >= 0);
        int cchunk = 0, tl = 0;
        if (do0) { cchunk = s / ch; tl = s - cchunk * ch; }

        // chunk gate: wait for producers, one acquire-inv per chunk
        if (do0 && tl == 0) {
            if (threadIdx.x == 0) {
                while (__hip_atomic_load(&g_sync[1088 + cchunk * 16],
                                         __ATOMIC_RELAXED, __HIP_MEMORY_SCOPE_AGENT) < NPROD)
                    __builtin_amdgcn_s_sleep(1);
                __builtin_amdgcn_fence(__ATOMIC_ACQUIRE, "agent");  // inv
            }
            __syncthreads();
        }

        // G prefetch (layer0 finalizer waves only), issued before the barrier
        float gpre[2][4];
        if (do0 && l == 0) {
            const _Float16* Gt = Gc + (size_t)(cchunk & 1) * slotsz + (size_t)tl * 4 * SLSZ;
#pragma unroll
            for (int tau = 0; tau < 2; ++tau)
#pragma unroll
                for (int r = 0; r < 4; ++r)
                    gpre[tau][r] = (float)Gt[(size_t)(rbase + r) * 4096 + tau * 2048 + colG0];
        }

        if (sidx > 0) grid_barrier(sidx, grp);
        if (do0 && tl == ch - 1 && threadIdx.x == 0)
            __hip_atomic_fetch_add(&g_sync[3136 + cchunk * 16], 1,
                                   __ATOMIC_RELAXED, __HIP_MEMORY_SCOPE_AGENT);

        // K-slice pass
        f32x4 acc0[4][2], acc1[4][2];
#pragma unroll
        for (int m = 0; m < 4; ++m)
#pragma unroll
            for (int tau = 0; tau < 2; ++tau) {
                acc0[m][tau] = f32x4{0.f, 0.f, 0.f, 0.f};
                acc1[m][tau] = f32x4{0.f, 0.f, 0.f, 0.f};
            }
        const _Float16* h0prev = ring0 + (size_t)((s - 1) & 1) * SLSZ;
        const _Float16* h1prev = ring1 + (size_t)((t1 - 1) & 1) * SLSZ;
        if (do0 && do1 && t1 > 0)
            kpass<0>(acc0, acc1, h0prev, nullptr, h1prev, nullptr,
                     bh0, bx1, bh1, wave, c16, quad);
        else if (do0 && !do1)   // s == 0
            kpass<1>(acc0, acc1, nullptr, hinit, nullptr, nullptr,
                     bh0, bx1, bh1, wave, c16, quad);
        else if (do0)           // s == 1
            kpass<2>(acc0, acc1, h0prev, nullptr, nullptr, hinit + SLSZ,
                     bh0, bx1, bh1, wave, c16, quad);
        else                    // s == SEQ (drain: layer1 only)
            kpass<3>(acc0, acc1, h0prev, nullptr, h1prev, nullptr,
                     bh0, bx1, bh1, wave, c16, quad);

        // publish partials, one sync, finalize
        if (do0)
#pragma unroll
            for (int m = 0; m < 4; ++m)
#pragma unroll
                for (int tau = 0; tau < 2; ++tau)
                    redA[wave][m][tau][lane] = acc0[m][tau];
        if (do1)
#pragma unroll
            for (int m = 0; m < 4; ++m)
#pragma unroll
                for (int tau = 0; tau < 2; ++tau)
                    redB[wave][m][tau][lane] = acc1[m][tau];
        __syncthreads();

        if (l == 0 && do0) {
            f32x4 fin[2];
#pragma unroll
            for (int tau = 0; tau < 2; ++tau) {
                f32x4 ssum = redA[0][mi][tau][lane];
#pragma unroll
                for (int v = 1; v < 8; ++v) ssum += redA[v][mi][tau][lane];
#pragma unroll
                for (int r = 0; r < 4; ++r) ssum[r] += gpre[tau][r];
                fin[tau] = ssum;
            }
            float* lh = (s == SEQ - 1) ? out + FO : nullptr;
            float* lc = (s == SEQ - 1) ? out + FO + 2 * SLSZ : nullptr;
            cell_epilogue(fin, creg, ring0 + (size_t)(s & 1) * SLSZ,
                          nullptr, lh, lc, rbase, hcol, c16, owner);
        }
        if (l == 1 && do1) {
            f32x4 fin[2];
#pragma unroll
            for (int tau = 0; tau < 2; ++tau) {
                f32x4 ssum = redB[0][mi][tau][lane];
#pragma unroll
                for (int v = 1; v < 8; ++v) ssum += redB[v][mi][tau][lane];
#pragma unroll
                for (int r = 0; r < 4; ++r) ssum[r] += bv1[tau];
                fin[tau] = ssum;
            }
            float* lh = (t1 == SEQ - 1) ? out + FO + SLSZ : nullptr;
            float* lc = (t1 == SEQ - 1) ? out + FO + 3 * SLSZ : nullptr;
            cell_epilogue(fin, creg, ring1 + (size_t)(t1 & 1) * SLSZ,
                          out + (size_t)t1 * SLSZ, lh, lc, rbase, hcol, c16, owner);
        }
        // next grid_barrier's syncthreads protects redA/redB WAR
    }
}

// ---- mega kernel: 32 producer + 128 consumer blocks, 512 threads -----------
__global__ __launch_bounds__(512, 2) void lstm_mega(
    const _Float16* __restrict__ WpX, const _Float16* __restrict__ WhR0,
    const _Float16* __restrict__ WxR1, const _Float16* __restrict__ WhR1,
    _Float16* __restrict__ Gc, const float* __restrict__ X,
    const float* __restrict__ hinit, const float* __restrict__ cinit,
    _Float16* __restrict__ ring, float* __restrict__ out,
    const float* __restrict__ bias0, const float* __restrict__ bias1,
    int nchunk, int ch)
{
    if (blockIdx.x < NPROD) {
        producer_path(WpX, X, bias0, Gc, nchunk, ch);
        return;
    }
    consumer_path((int)blockIdx.x - NPROD, WhR0, WxR1, WhR1, Gc,
                  hinit, cinit, ring, out, bias1, ch);
}

extern "C" void kernel_launch(void* const* d_in, const int* in_sizes, int n_in,
                              void* d_out, int out_size, void* d_ws, size_t ws_size,
                              hipStream_t stream) {
    const float* X  = (const float*)d_in[0];
    const float* h0 = (const float*)d_in[1];
    const float* c0 = (const float*)d_in[2];
    const float* W  = (const float*)d_in[3];
    const float* bb = (const float*)d_in[4];
    float* out = (float*)d_out;
    char* ws = (char*)d_ws;

    const size_t FIXED = 34603008ULL;
    int CH = 0;
    if (ws_size >= FIXED + 2ULL * 8 * 524288ULL)      CH = 8;   // 2 slots x 4 MB
    else if (ws_size >= FIXED + 2ULL * 4 * 524288ULL) CH = 4;   // 2 slots x 2 MB
    if (CH == 0) {
        zero_out<<<dim3(33024), 256, 0, stream>>>(out);
        return;
    }

    _Float16* WpX  = (_Float16*)(ws + 0);
    _Float16* WhR0 = (_Float16*)(ws + 8388608);
    _Float16* WxR1 = (_Float16*)(ws + 16777216);
    _Float16* WhR1 = (_Float16*)(ws + 25165824);
    _Float16* ring = (_Float16*)(ws + 33554432);
    _Float16* Gc   = (_Float16*)(ws + 34603008);

    const size_t MSTRIDE = 2048ULL * 4096ULL;   // per-layer W block (floats)

    pack1<<<dim3(256, 8), 256, 0, stream>>>(W, WpX);                             // Wx0
    pack_wh<<<dim3(NCONS, 8), 256, 0, stream>>>(W + 1024 * 4096, WhR0);          // Wh0
    pack_wh<<<dim3(NCONS, 8), 256, 0, stream>>>(W + MSTRIDE, WxR1);              // Wx1
    pack_wh<<<dim3(NCONS, 8), 256, 0, stream>>>(W + MSTRIDE + 1024 * 4096, WhR1);// Wh1
    init_bar_k<<<dim3(1), 256, 0, stream>>>();

    lstm_mega<<<dim3(NPROD + NCONS), 512, 0, stream>>>(
        WpX, WhR0, WxR1, WhR1, Gc, X, h0, c0, ring, out,
        bb, bb + 4096, SEQ / CH, CH);
}